// Round 1
// baseline (469.135 us; speedup 1.0000x reference)
//
#include <hip/hip_runtime.h>
#include <math.h>

// SpatialAttention: B=4, C=64, H=W=64, N=4096, fp32.
// k1: qkv projection into d_ws ([B,C,N] each).
// k2: flash-style fused attention, 64-query tile per block, online softmax.

constexpr int C_ = 64;
constexpr int N_ = 4096;

__global__ __launch_bounds__(256) void qkv_proj_kernel(
    const float* __restrict__ x,
    const float* __restrict__ Wq, const float* __restrict__ bq,
    const float* __restrict__ Wk, const float* __restrict__ bk,
    const float* __restrict__ Wv, const float* __restrict__ bv,
    float* __restrict__ q, float* __restrict__ k, float* __restrict__ v)
{
    __shared__ float xs[64][65];
    const int b  = blockIdx.x >> 6;          // blockIdx.x = b*64 + ntile
    const int n0 = (blockIdx.x & 63) << 6;
    const int t  = threadIdx.x;
    const long xbase = (long)b * (C_ * N_);

    // load x tile [64c x 64n], coalesced (64 consecutive n per wave)
    const int nl = t & 63, cb = t >> 6;
    #pragma unroll
    for (int it = 0; it < 16; ++it) {
        int c = it * 4 + cb;
        xs[c][nl] = x[xbase + (long)c * N_ + n0 + nl];
    }
    __syncthreads();

    const int n  = t & 63;
    const int ob = (t >> 6) << 4;            // 0,16,32,48
    for (int oo = 0; oo < 16; ++oo) {
        const int o = ob + oo;
        const float* __restrict__ wq = Wq + o * C_;
        const float* __restrict__ wk = Wk + o * C_;
        const float* __restrict__ wv = Wv + o * C_;
        float aq = bq[o], ak = bk[o], av = bv[o];
        #pragma unroll 8
        for (int c = 0; c < C_; ++c) {
            float xv = xs[c][n];
            aq += wq[c] * xv;   // W loads are wave-uniform -> scalar loads
            ak += wk[c] * xv;
            av += wv[c] * xv;
        }
        long obase = xbase + (long)o * N_ + n0 + n;
        q[obase] = aq; k[obase] = ak; v[obase] = av;
    }
}

__global__ __launch_bounds__(256) void attn_kernel(
    const float* __restrict__ q, const float* __restrict__ k,
    const float* __restrict__ v, const float* __restrict__ x,
    const float* __restrict__ gamma_p, float* __restrict__ out)
{
    // stride 68: keeps float4 (16B) alignment of rows (272B = 17*16)
    __shared__ float qs [64][68];   // [c][i]
    __shared__ float ks [64][68];   // [c][j]
    __shared__ float vst[64][68];   // [j][c]  (V transposed)
    __shared__ float pst[64][68];   // [j][i]  (P transposed)

    const int b  = blockIdx.y;
    const int i0 = blockIdx.x << 6;
    const int t  = threadIdx.x;
    const int tj = t & 15;          // S col group (j), O row group (c)
    const int ti = t >> 4;          // S row group (i), O col group (i)
    const long bbase = (long)b * (C_ * N_);

    // ---- load Q tile (coalesced) ----
    const int ll = t & 63, cb = t >> 6;
    #pragma unroll
    for (int it = 0; it < 16; ++it) {
        int c = it * 4 + cb;
        qs[c][ll] = q[bbase + (long)c * N_ + i0 + ll];
    }

    float o_acc[4][4];              // [cc][aa]: c = tj*4+cc, i = ti*4+aa
    #pragma unroll
    for (int a = 0; a < 4; ++a)
        #pragma unroll
        for (int bb = 0; bb < 4; ++bb) o_acc[a][bb] = 0.f;
    float m_run[4], l_run[4];
    #pragma unroll
    for (int a = 0; a < 4; ++a) { m_run[a] = -1e30f; l_run[a] = 0.f; }

    for (int jt = 0; jt < 64; ++jt) {
        const int j0 = jt << 6;
        __syncthreads();            // prev-iter consumers of ks/vst/pst done

        // ---- load K,V j-tile ----
        #pragma unroll
        for (int it = 0; it < 16; ++it) {
            int c = it * 4 + cb;
            long g = bbase + (long)c * N_ + j0 + ll;
            float kv = k[g];
            float vv = v[g];
            ks[c][ll]  = kv;
            vst[ll][c] = vv;        // transposed store (8-way bank alias, 16 insts)
        }
        __syncthreads();

        // ---- S = Q^T K : s[aa][bb], i = ti*4+aa, j = tj*4+bb ----
        float s[4][4];
        #pragma unroll
        for (int a = 0; a < 4; ++a)
            #pragma unroll
            for (int bb = 0; bb < 4; ++bb) s[a][bb] = 0.f;
        #pragma unroll 4
        for (int c = 0; c < C_; ++c) {
            float4 q4 = *(const float4*)&qs[c][ti * 4];
            float4 k4 = *(const float4*)&ks[c][tj * 4];
            float qa[4] = {q4.x, q4.y, q4.z, q4.w};
            float kb[4] = {k4.x, k4.y, k4.z, k4.w};
            #pragma unroll
            for (int a = 0; a < 4; ++a)
                #pragma unroll
                for (int bb = 0; bb < 4; ++bb)
                    s[a][bb] += qa[a] * kb[bb];
        }

        // ---- online softmax, per row i = ti*4+a ----
        // the 16 threads holding row i are 16 consecutive lanes -> shfl_xor
        float mnew[4], alpha[4];
        #pragma unroll
        for (int a = 0; a < 4; ++a) {
            float rm = fmaxf(fmaxf(s[a][0], s[a][1]), fmaxf(s[a][2], s[a][3]));
            rm = fmaxf(rm, __shfl_xor(rm, 1));
            rm = fmaxf(rm, __shfl_xor(rm, 2));
            rm = fmaxf(rm, __shfl_xor(rm, 4));
            rm = fmaxf(rm, __shfl_xor(rm, 8));
            mnew[a]  = fmaxf(m_run[a], rm);
            alpha[a] = __expf(m_run[a] - mnew[a]);
            m_run[a] = mnew[a];
        }
        #pragma unroll
        for (int a = 0; a < 4; ++a) {
            float rs = 0.f;
            #pragma unroll
            for (int bb = 0; bb < 4; ++bb) {
                s[a][bb] = __expf(s[a][bb] - mnew[a]);
                rs += s[a][bb];
            }
            rs += __shfl_xor(rs, 1);
            rs += __shfl_xor(rs, 2);
            rs += __shfl_xor(rs, 4);
            rs += __shfl_xor(rs, 8);
            l_run[a] = l_run[a] * alpha[a] + rs;
        }
        // write P transposed: pst[j][i]
        #pragma unroll
        for (int bb = 0; bb < 4; ++bb) {
            float4 pv = make_float4(s[0][bb], s[1][bb], s[2][bb], s[3][bb]);
            *(float4*)&pst[tj * 4 + bb][ti * 4] = pv;
        }
        // rescale O by alpha (alpha indexed by i = ti*4+aa -> in registers)
        #pragma unroll
        for (int cc = 0; cc < 4; ++cc)
            #pragma unroll
            for (int a = 0; a < 4; ++a)
                o_acc[cc][a] *= alpha[a];
        __syncthreads();

        // ---- O[c][i] += sum_j V^T[j][c] * P^T[j][i] ----
        #pragma unroll 4
        for (int j = 0; j < 64; ++j) {
            float4 v4 = *(const float4*)&vst[j][tj * 4];
            float4 p4 = *(const float4*)&pst[j][ti * 4];
            float vc[4] = {v4.x, v4.y, v4.z, v4.w};
            float pa[4] = {p4.x, p4.y, p4.z, p4.w};
            #pragma unroll
            for (int cc = 0; cc < 4; ++cc)
                #pragma unroll
                for (int a = 0; a < 4; ++a)
                    o_acc[cc][a] += vc[cc] * pa[a];
        }
    }

    // ---- epilogue: out = gamma * O/l + x ----
    const float g = gamma_p[0];
    float inv_l[4];
    #pragma unroll
    for (int a = 0; a < 4; ++a) inv_l[a] = 1.0f / l_run[a];
    #pragma unroll
    for (int cc = 0; cc < 4; ++cc) {
        int c = tj * 4 + cc;
        long base = bbase + (long)c * N_ + i0 + ti * 4;
        float4 xr = *(const float4*)&x[base];
        float4 r;
        r.x = g * o_acc[cc][0] * inv_l[0] + xr.x;
        r.y = g * o_acc[cc][1] * inv_l[1] + xr.y;
        r.z = g * o_acc[cc][2] * inv_l[2] + xr.z;
        r.w = g * o_acc[cc][3] * inv_l[3] + xr.w;
        *(float4*)&out[base] = r;
    }
}

extern "C" void kernel_launch(void* const* d_in, const int* in_sizes, int n_in,
                              void* d_out, int out_size, void* d_ws, size_t ws_size,
                              hipStream_t stream) {
    const float* x  = (const float*)d_in[0];
    const float* Wq = (const float*)d_in[1];
    const float* bq = (const float*)d_in[2];
    const float* Wk = (const float*)d_in[3];
    const float* bk = (const float*)d_in[4];
    const float* Wv = (const float*)d_in[5];
    const float* bv = (const float*)d_in[6];
    const float* gm = (const float*)d_in[7];
    float* out = (float*)d_out;

    const int B = in_sizes[0] / (C_ * N_);   // 4
    const long per = (long)B * C_ * N_;      // 1,048,576 floats = 4 MB
    float* q = (float*)d_ws;
    float* k = q + per;
    float* v = k + per;                      // needs 12 MB of ws

    qkv_proj_kernel<<<B * 64, 256, 0, stream>>>(x, Wq, bq, Wk, bk, Wv, bv, q, k, v);
    attn_kernel<<<dim3(64, B), 256, 0, stream>>>(q, k, v, x, gm, out);
}

// Round 2
// 243.080 us; speedup vs baseline: 1.9300x; 1.9300x over previous
//
#include <hip/hip_runtime.h>
#include <hip/hip_bf16.h>
#include <math.h>

// SpatialAttention fp32 B=4,C=64,N=4096 via bf16 MFMA flash attention.
// prep:    q,k,v projections; q scaled by log2e; q,k split hi/lo bf16;
//          q_t [b][n][c]; k,v in 16B-chunk interleaved layouts for staging.
// attn:    i-tile 256 (4 waves x 64 rows), j-chunk split (js=8), fixed-max
//          softmax exp2(s - 86.56), partial O/l per chunk.
// combine: sum partials, out = gamma*O/l + x (LDS transpose for coalescing).

constexpr int C_ = 64;
constexpr int N_ = 4096;
constexpr float LOG2E = 1.4426950408889634f;
constexpr float MBIAS = 86.5617f;   // 60 * log2(e)

typedef float  f4 __attribute__((ext_vector_type(4)));
typedef short  s8 __attribute__((ext_vector_type(8)));

__device__ inline unsigned short f2bf(float x) {
    union { float f; unsigned u; } a; a.f = x;
    unsigned r = a.u + 0x7FFFu + ((a.u >> 16) & 1u);   // RNE
    return (unsigned short)(r >> 16);
}
__device__ inline float bf2f(unsigned short h) {
    union { float f; unsigned u; } a; a.u = ((unsigned)h) << 16; return a.f;
}

// ---------------- prep ----------------
__global__ __launch_bounds__(256) void prep_kernel(
    const float* __restrict__ x,
    const float* __restrict__ Wq, const float* __restrict__ bq,
    const float* __restrict__ Wk, const float* __restrict__ bk,
    const float* __restrict__ Wv, const float* __restrict__ bv,
    unsigned short* __restrict__ qhi, unsigned short* __restrict__ qlo,
    unsigned short* __restrict__ khi, unsigned short* __restrict__ klo,
    unsigned short* __restrict__ vv)
{
    __shared__ float xs[64][65];
    __shared__ float qs[16][65];
    __shared__ float ks2[16][65];
    const int t  = threadIdx.x;
    const int nt = blockIdx.x;          // n-tile (64 n's)
    const int os = blockIdx.y;          // o-slice (16 o's)
    const int b  = blockIdx.z;
    const int n0 = nt * 64;
    const long xbase = (long)b * (C_ * N_);

    {   // load x tile [64c][64n]
        const int nl = t & 63, cb = t >> 6;
        #pragma unroll
        for (int it = 0; it < 16; ++it) {
            int c = it * 4 + cb;
            xs[c][nl] = x[xbase + (long)c * N_ + n0 + nl];
        }
    }
    __syncthreads();

    const int n   = t & 63;
    const int ol0 = (t >> 6) * 4;       // 4 o's per thread
    float aq[4], ak[4], av[4];
    #pragma unroll
    for (int i = 0; i < 4; ++i) {
        int o = os * 16 + ol0 + i;
        aq[i] = bq[o]; ak[i] = bk[o]; av[i] = bv[o];
    }
    #pragma unroll 8
    for (int c = 0; c < C_; ++c) {
        float xv = xs[c][n];
        #pragma unroll
        for (int i = 0; i < 4; ++i) {
            int o = os * 16 + ol0 + i;
            aq[i] = fmaf(Wq[o * 64 + c], xv, aq[i]);
            ak[i] = fmaf(Wk[o * 64 + c], xv, ak[i]);
            av[i] = fmaf(Wv[o * 64 + c], xv, av[i]);
        }
    }
    const long vbB = (long)b * (N_ * C_);
    #pragma unroll
    for (int i = 0; i < 4; ++i) {
        int o = os * 16 + ol0 + i;
        qs [ol0 + i][n] = aq[i] * LOG2E;
        ks2[ol0 + i][n] = ak[i];
        // v interleaved: chunk = jblk*512 + (jloc>>3)*64 + c ; elem = chunk*8 + (j&7)
        long e = vbB + (long)(n0 >> 6) * 4096 + (long)(n >> 3) * 512 + (long)o * 8 + (n & 7);
        vv[e] = f2bf(av[i]);
    }
    __syncthreads();

    // transposed writes: thread -> row r (n or j local), 4 channels
    const int r   = t >> 2;             // 0..63
    const int cl0 = (t & 3) * 4;        // local c offset within the 16-o slice
    unsigned short hq[4], lq[4], hk[4], lk[4];
    #pragma unroll
    for (int cc = 0; cc < 4; ++cc) {
        float vq = qs[cl0 + cc][r];
        unsigned short h = f2bf(vq);
        hq[cc] = h; lq[cc] = f2bf(vq - bf2f(h));
        float vk = ks2[cl0 + cc][r];
        unsigned short h2 = f2bf(vk);
        hk[cc] = h2; lk[cc] = f2bf(vk - bf2f(h2));
    }
    // q_t [b][i][c]
    {
        long qoff = ((long)b * N_ + n0 + r) * 64 + os * 16 + cl0;
        uint2 p;
        p.x = (unsigned)hq[0] | ((unsigned)hq[1] << 16);
        p.y = (unsigned)hq[2] | ((unsigned)hq[3] << 16);
        *(uint2*)(qhi + qoff) = p;
        p.x = (unsigned)lq[0] | ((unsigned)lq[1] << 16);
        p.y = (unsigned)lq[2] | ((unsigned)lq[3] << 16);
        *(uint2*)(qlo + qoff) = p;
    }
    // k interleaved: chunk = b*32768 + jblk*512 + (c>>3)*64 + jloc ; elem = chunk*8 + (c&7)
    {
        int c0 = os * 16 + cl0;
        long koff = ((long)b * 32768 + (long)(n0 >> 6) * 512 + (c0 >> 3) * 64 + r) * 8 + (c0 & 7);
        uint2 p;
        p.x = (unsigned)hk[0] | ((unsigned)hk[1] << 16);
        p.y = (unsigned)hk[2] | ((unsigned)hk[3] << 16);
        *(uint2*)(khi + koff) = p;
        p.x = (unsigned)lk[0] | ((unsigned)lk[1] << 16);
        p.y = (unsigned)lk[2] | ((unsigned)lk[3] << 16);
        *(uint2*)(klo + koff) = p;
    }
}

// ---------------- attention ----------------
__global__ __launch_bounds__(256, 2) void attn_kernel(
    const unsigned short* __restrict__ qhi, const unsigned short* __restrict__ qlo,
    const unsigned short* __restrict__ khi, const unsigned short* __restrict__ klo,
    const unsigned short* __restrict__ vv,
    float* __restrict__ Opart, float* __restrict__ lpart,
    int njt, int Bn)
{
    // LDS: ks_hi 8K | ks_lo 8K | vs 8K | pst 4*9216 (stride 144B, 64 rows)
    __shared__ __align__(16) char smem[61440];
    char* ks_hi = smem;
    char* ks_lo = smem + 8192;
    char* vsm   = smem + 16384;

    const int t  = threadIdx.x;
    const int w  = t >> 6;
    const int L  = t & 63;
    const int lh = L >> 4, ll = L & 15;
    const int b  = blockIdx.z, jc = blockIdx.y;
    const int i0 = blockIdx.x * 256;
    const int iw = i0 + w * 64;
    char* pst = smem + 24576 + w * 9216;

    // Q A-frags (held in registers for whole kernel)
    s8 qh[4][2], ql[4][2];
    #pragma unroll
    for (int m = 0; m < 4; ++m)
        #pragma unroll
        for (int ks = 0; ks < 2; ++ks) {
            long off = ((long)b * N_ + iw + m * 16 + ll) * 64 + ks * 32 + lh * 8;
            qh[m][ks] = *(const s8*)(qhi + off);
            ql[m][ks] = *(const s8*)(qlo + off);
        }

    f4 O[4][4];
    #pragma unroll
    for (int m = 0; m < 4; ++m)
        #pragma unroll
        for (int nn = 0; nn < 4; ++nn)
            O[m][nn] = (f4){0.f, 0.f, 0.f, 0.f};
    float lp[4][4];
    #pragma unroll
    for (int m = 0; m < 4; ++m)
        #pragma unroll
        for (int r = 0; r < 4; ++r) lp[m][r] = 0.f;

    const long cbase = (long)b * 32768;      // 16B-chunk base of this batch
    const int jt0 = jc * njt;
    uint4 pk[6];
    {
        const uint4* gk = (const uint4*)khi + cbase + (long)jt0 * 512;
        const uint4* gl = (const uint4*)klo + cbase + (long)jt0 * 512;
        const uint4* gv = (const uint4*)vv  + cbase + (long)jt0 * 512;
        pk[0] = gk[t]; pk[1] = gk[t + 256];
        pk[2] = gl[t]; pk[3] = gl[t + 256];
        pk[4] = gv[t]; pk[5] = gv[t + 256];
    }

    for (int jt = 0; jt < njt; ++jt) {
        __syncthreads();                      // previous tile fully consumed
        ((uint4*)ks_hi)[t] = pk[0]; ((uint4*)ks_hi)[t + 256] = pk[1];
        ((uint4*)ks_lo)[t] = pk[2]; ((uint4*)ks_lo)[t + 256] = pk[3];
        ((uint4*)vsm  )[t] = pk[4]; ((uint4*)vsm  )[t + 256] = pk[5];
        __syncthreads();
        if (jt + 1 < njt) {                   // prefetch next tile into regs
            const uint4* gk = (const uint4*)khi + cbase + (long)(jt0 + jt + 1) * 512;
            const uint4* gl = (const uint4*)klo + cbase + (long)(jt0 + jt + 1) * 512;
            const uint4* gv = (const uint4*)vv  + cbase + (long)(jt0 + jt + 1) * 512;
            pk[0] = gk[t]; pk[1] = gk[t + 256];
            pk[2] = gl[t]; pk[3] = gl[t + 256];
            pk[4] = gv[t]; pk[5] = gv[t + 256];
        }

        // ---- S = Q^T K (3-pass split bf16), softmax, P -> pst ----
        #pragma unroll
        for (int js = 0; js < 4; ++js) {
            s8 bh[2], bl[2];
            #pragma unroll
            for (int ks = 0; ks < 2; ++ks) {
                int ch = (ks * 4 + lh) * 64 + js * 16 + ll;
                bh[ks] = *(const s8*)(ks_hi + ch * 16);
                bl[ks] = *(const s8*)(ks_lo + ch * 16);
            }
            #pragma unroll
            for (int m = 0; m < 4; ++m) {
                f4 acc = (f4){0.f, 0.f, 0.f, 0.f};
                acc = __builtin_amdgcn_mfma_f32_16x16x32_bf16(qh[m][0], bh[0], acc, 0, 0, 0);
                acc = __builtin_amdgcn_mfma_f32_16x16x32_bf16(qh[m][1], bh[1], acc, 0, 0, 0);
                acc = __builtin_amdgcn_mfma_f32_16x16x32_bf16(qh[m][0], bl[0], acc, 0, 0, 0);
                acc = __builtin_amdgcn_mfma_f32_16x16x32_bf16(qh[m][1], bl[1], acc, 0, 0, 0);
                acc = __builtin_amdgcn_mfma_f32_16x16x32_bf16(ql[m][0], bh[0], acc, 0, 0, 0);
                acc = __builtin_amdgcn_mfma_f32_16x16x32_bf16(ql[m][1], bh[1], acc, 0, 0, 0);
                float p[4], pp[4];
                #pragma unroll
                for (int r = 0; r < 4; ++r) {
                    p[r] = exp2f(acc[r] - MBIAS);
                    lp[m][r] += p[r];
                    pp[r] = __shfl_xor(p[r], 1);
                }
                // paired-lane packed bf16x2 writes (C-layout -> pst [i][j])
                #pragma unroll
                for (int r2 = 0; r2 < 2; ++r2) {
                    int r = r2 * 2 + (ll & 1);
                    float a  = (ll & 1) ? pp[r] : p[r];     // even col value
                    float c2 = (ll & 1) ? p[r] : pp[r];     // odd col value
                    __hip_bfloat162 hb = __float22bfloat162_rn(make_float2(a, c2));
                    unsigned pu = *(unsigned*)&hb;
                    int row  = m * 16 + lh * 4 + r;
                    int col2 = js * 16 + (ll & ~1);
                    *(unsigned*)(pst + row * 144 + col2 * 2) = pu;
                }
            }
        }

        // ---- O += P V (A from pst, B from vs) ----
        #pragma unroll
        for (int ks = 0; ks < 2; ++ks) {
            s8 bv[4];
            #pragma unroll
            for (int nn = 0; nn < 4; ++nn) {
                int ch = (ks * 4 + lh) * 64 + nn * 16 + ll;
                bv[nn] = *(const s8*)(vsm + ch * 16);
            }
            #pragma unroll
            for (int m = 0; m < 4; ++m) {
                s8 ap = *(const s8*)(pst + (m * 16 + ll) * 144 + ks * 64 + lh * 16);
                #pragma unroll
                for (int nn = 0; nn < 4; ++nn)
                    O[m][nn] = __builtin_amdgcn_mfma_f32_16x16x32_bf16(ap, bv[nn], O[m][nn], 0, 0, 0);
            }
        }
    }

    // ---- epilogue: reduce l over the 16 j-lanes, store partials ----
    #pragma unroll
    for (int m = 0; m < 4; ++m)
        #pragma unroll
        for (int r = 0; r < 4; ++r) {
            float s = lp[m][r];
            s += __shfl_xor(s, 1); s += __shfl_xor(s, 2);
            s += __shfl_xor(s, 4); s += __shfl_xor(s, 8);
            lp[m][r] = s;
        }
    const long pbase = ((long)jc * Bn + b) * N_;
    if (ll == 0) {
        #pragma unroll
        for (int m = 0; m < 4; ++m)
            #pragma unroll
            for (int r = 0; r < 4; ++r)
                lpart[pbase + iw + m * 16 + lh * 4 + r] = lp[m][r];
    }
    #pragma unroll
    for (int m = 0; m < 4; ++m)
        #pragma unroll
        for (int nn = 0; nn < 4; ++nn)
            #pragma unroll
            for (int r = 0; r < 4; ++r)
                Opart[(pbase + iw + m * 16 + lh * 4 + r) * 64 + nn * 16 + ll] = O[m][nn][r];
}

// ---------------- combine ----------------
__global__ __launch_bounds__(256) void combine_kernel(
    const float* __restrict__ Opart, const float* __restrict__ lpart,
    const float* __restrict__ x, const float* __restrict__ gamma_p,
    float* __restrict__ out, int js, int Bn)
{
    __shared__ float trn[64][65];
    const int t  = threadIdx.x;
    const int nt = blockIdx.x, b = blockIdx.y;
    const int n0 = nt * 64;
    const float g = gamma_p[0];
    const int nl = t >> 2, c16 = (t & 3) * 16;

    float acc[16];
    #pragma unroll
    for (int i = 0; i < 16; ++i) acc[i] = 0.f;
    float lsum = 0.f;
    for (int s = 0; s < js; ++s) {
        long rbase = (((long)s * Bn + b) * N_ + n0 + nl) * 64 + c16;
        #pragma unroll
        for (int q = 0; q < 4; ++q) {
            float4 v = *(const float4*)(Opart + rbase + q * 4);
            acc[q*4+0] += v.x; acc[q*4+1] += v.y; acc[q*4+2] += v.z; acc[q*4+3] += v.w;
        }
        lsum += lpart[((long)s * Bn + b) * N_ + n0 + nl];
    }
    float inv = g / lsum;
    #pragma unroll
    for (int i = 0; i < 16; ++i) trn[c16 + i][nl] = acc[i] * inv;
    __syncthreads();

    const int cl = t >> 2, nq = (t & 3) * 16;
    long obase = ((long)b * 64 + cl) * N_ + n0 + nq;
    #pragma unroll
    for (int q = 0; q < 4; ++q) {
        float4 xr = *(const float4*)(x + obase + q * 4);
        float4 r;
        r.x = trn[cl][nq + q*4 + 0] + xr.x;
        r.y = trn[cl][nq + q*4 + 1] + xr.y;
        r.z = trn[cl][nq + q*4 + 2] + xr.z;
        r.w = trn[cl][nq + q*4 + 3] + xr.w;
        *(float4*)(out + obase + q * 4) = r;
    }
}

extern "C" void kernel_launch(void* const* d_in, const int* in_sizes, int n_in,
                              void* d_out, int out_size, void* d_ws, size_t ws_size,
                              hipStream_t stream) {
    const float* x  = (const float*)d_in[0];
    const float* Wq = (const float*)d_in[1];
    const float* bq = (const float*)d_in[2];
    const float* Wk = (const float*)d_in[3];
    const float* bk = (const float*)d_in[4];
    const float* Wv = (const float*)d_in[5];
    const float* bv = (const float*)d_in[6];
    const float* gm = (const float*)d_in[7];
    float* out = (float*)d_out;

    const int B = in_sizes[0] / (C_ * N_);           // 4
    const size_t per = (size_t)B * N_ * C_;          // 1M elements
    char* w = (char*)d_ws;
    unsigned short* qhi = (unsigned short*)w;
    unsigned short* qlo = qhi + per;
    unsigned short* khi = qlo + per;
    unsigned short* klo = khi + per;
    unsigned short* vv  = klo + per;                 // 5 * 2 MB = 10 MB
    size_t base = 5 * per * sizeof(unsigned short);

    int js = 8;
    while (js > 1) {
        size_t need = base + (size_t)js * (per * sizeof(float) + (size_t)B * N_ * sizeof(float));
        if (need <= ws_size) break;
        js >>= 1;
    }
    float* Opart = (float*)(w + base);
    float* lpart = (float*)(w + base + (size_t)js * per * sizeof(float));

    prep_kernel<<<dim3(64, 4, B), 256, 0, stream>>>(x, Wq, bq, Wk, bk, Wv, bv,
                                                    qhi, qlo, khi, klo, vv);
    attn_kernel<<<dim3(16, js, B), 256, 0, stream>>>(qhi, qlo, khi, klo, vv,
                                                     Opart, lpart, 64 / js, B);
    combine_kernel<<<dim3(64, B), 256, 0, stream>>>(Opart, lpart, x, gm, out, js, B);
}